// Round 11
// baseline (343.582 us; speedup 1.0000x reference)
//
#include <hip/hip_runtime.h>
#include <hip/hip_bf16.h>
#include <math.h>

#define L_SEQ  2048
#define NTOK   4096
#define DMODEL 512
#define DINNER 1024
#define DSTATE 16
#define NCHUNK 64
#define CHUNK  32

typedef unsigned short u16;
typedef float f32x4 __attribute__((ext_vector_type(4)));
typedef __bf16 bf16x8 __attribute__((ext_vector_type(8)));

__device__ __forceinline__ float sigmoidf_(float x) {
    return 1.0f / (1.0f + __expf(-x));
}
__device__ __forceinline__ u16 f2bf(float f) {
    __hip_bfloat16 h = __float2bfloat16(f);
    return __builtin_bit_cast(u16, h);
}
__device__ __forceinline__ float bf2f(u16 u) {
    return __bfloat162float(__builtin_bit_cast(__hip_bfloat16, u));
}
__device__ __forceinline__ float softplus_fast(float t) {
    return fmaxf(t, 0.0f) + __logf(1.0f + __expf(-fabsf(t)));
}
__device__ __forceinline__ void gload_lds16(const u16* g, u16* l) {
    __builtin_amdgcn_global_load_lds(
        (const __attribute__((address_space(1))) void*)g,
        (__attribute__((address_space(3))) void*)l, 16, 0, 0);
}

// ---------------------------------------------------------------------------
// Transpose + cast fp32 [R][C] -> bf16 [C][R]
// ---------------------------------------------------------------------------
__global__ __launch_bounds__(256) void tcast_k(const float* __restrict__ in,
                                               u16* __restrict__ out,
                                               int R, int C)
{
    __shared__ u16 t[32][33];
    const int cl = threadIdx.x & 31;
    const int rl = threadIdx.x >> 5;
    const int bc = blockIdx.x << 5;
    const int br = blockIdx.y << 5;
    #pragma unroll
    for (int i = 0; i < 4; ++i) {
        int r = rl + i * 8;
        t[r][cl] = f2bf(in[(size_t)(br + r) * C + bc + cl]);
    }
    __syncthreads();
    #pragma unroll
    for (int i = 0; i < 4; ++i) {
        int r = rl + i * 8;
        out[(size_t)(bc + r) * R + br + cl] = t[cl][r];
    }
}

// ---------------------------------------------------------------------------
// Plain cast fp32 -> bf16 (8 elems/thread)
// ---------------------------------------------------------------------------
__global__ __launch_bounds__(256) void castbf_k(const float* __restrict__ in,
                                                u16* __restrict__ out)
{
    const int i = blockIdx.x * 256 + threadIdx.x;
    float4 a = *(const float4*)(in + (size_t)i * 8);
    float4 b = *(const float4*)(in + (size_t)i * 8 + 4);
    uint p0 = (uint)f2bf(a.x) | ((uint)f2bf(a.y) << 16);
    uint p1 = (uint)f2bf(a.z) | ((uint)f2bf(a.w) << 16);
    uint p2 = (uint)f2bf(b.x) | ((uint)f2bf(b.y) << 16);
    uint p3 = (uint)f2bf(b.z) | ((uint)f2bf(b.w) << 16);
    *(uint4*)(out + (size_t)i * 8) = make_uint4(p0, p1, p2, p3);
}

// ---------------------------------------------------------------------------
// LayerNorm -> bf16 output
// ---------------------------------------------------------------------------
__global__ __launch_bounds__(256) void ln_k(const float* __restrict__ x,
                                            const float* __restrict__ g,
                                            const float* __restrict__ b,
                                            u16* __restrict__ xn)
{
    const int w    = threadIdx.x >> 6;
    const int lane = threadIdx.x & 63;
    const int row  = (blockIdx.x << 2) + w;
    const float* xr = x + (size_t)row * DMODEL;

    float4 v0 = *(const float4*)(xr + lane * 8);
    float4 v1 = *(const float4*)(xr + lane * 8 + 4);

    float s = v0.x + v0.y + v0.z + v0.w + v1.x + v1.y + v1.z + v1.w;
    #pragma unroll
    for (int o = 1; o < 64; o <<= 1) s += __shfl_xor(s, o, 64);
    const float mu = s * (1.0f / DMODEL);

    float d0 = v0.x - mu, d1 = v0.y - mu, d2 = v0.z - mu, d3 = v0.w - mu;
    float d4 = v1.x - mu, d5 = v1.y - mu, d6 = v1.z - mu, d7 = v1.w - mu;
    float ss = d0*d0 + d1*d1 + d2*d2 + d3*d3 + d4*d4 + d5*d5 + d6*d6 + d7*d7;
    #pragma unroll
    for (int o = 1; o < 64; o <<= 1) ss += __shfl_xor(ss, o, 64);
    const float rs = rsqrtf(ss * (1.0f / DMODEL) + 1e-5f);

    float4 g0 = *(const float4*)(g + lane * 8);
    float4 g1 = *(const float4*)(g + lane * 8 + 4);
    float4 b0 = *(const float4*)(b + lane * 8);
    float4 b1 = *(const float4*)(b + lane * 8 + 4);

    u16 o8[8];
    o8[0] = f2bf(d0 * rs * g0.x + b0.x);
    o8[1] = f2bf(d1 * rs * g0.y + b0.y);
    o8[2] = f2bf(d2 * rs * g0.z + b0.z);
    o8[3] = f2bf(d3 * rs * g0.w + b0.w);
    o8[4] = f2bf(d4 * rs * g1.x + b1.x);
    o8[5] = f2bf(d5 * rs * g1.y + b1.y);
    o8[6] = f2bf(d6 * rs * g1.z + b1.z);
    o8[7] = f2bf(d7 * rs * g1.w + b1.w);
    uint pk0 = (uint)o8[0] | ((uint)o8[1] << 16);
    uint pk1 = (uint)o8[2] | ((uint)o8[3] << 16);
    uint pk2 = (uint)o8[4] | ((uint)o8[5] << 16);
    uint pk3 = (uint)o8[6] | ((uint)o8[7] << 16);
    uint4 pk = make_uint4(pk0, pk1, pk2, pk3);
    *(uint4*)(xn + (size_t)row * DMODEL + lane * 8) = pk;
}

// ---------------------------------------------------------------------------
// bf16 MFMA GEMM: C[M,N] = A[M,K] (bf16 rm) x B^T[N,K] (bf16 rm)
// 2-phase double-buffered global_load_lds pipeline; XOR-swizzle on global
// source slot (m173); XCD-aware bijective block swizzle; coalesced epilogue.
// EPI: 1 = fp32 + bf16 dual store, 2 = softplus(acc+bias)->bf16,
//      3 = acc+bias+resid->fp32, 4 = bf16 store
// ---------------------------------------------------------------------------
template<int BM, int BN, int BK, int WGM, int WGN, int EPI, bool BR2, bool DUAL>
__global__ __launch_bounds__(256) void gemm_bf16_k(
    const u16* __restrict__ A0, const u16* __restrict__ A1, int lda,
    const u16* __restrict__ B0, const u16* __restrict__ B1, int ldb,
    float* __restrict__ C0f, float* __restrict__ C1f,
    u16* __restrict__ C0h, u16* __restrict__ C1h, int ldc,
    int K,
    const float* __restrict__ bias0, const float* __restrict__ bias1,
    const float* __restrict__ resid)
{
    constexpr int SPR   = BK / 8;
    constexpr int SMASK = SPR - 1;
    constexpr int IA    = BM * SPR / 256;
    constexpr int IB    = BN * SPR / 256;
    constexpr int WTM   = BM / WGM;
    constexpr int WTN   = BN / WGN;
    constexpr int FM    = WTM / 16;
    constexpr int FN    = WTN / 16;
    constexpr int KH    = BK / 32;
    constexpr bool F32S = (EPI == 1 || EPI == 3);
    constexpr int RPF   = WTN + 4;
    constexpr int RPH   = WTN + 8;
    constexpr int NCF   = WTN / 16;
    constexpr int NCH   = WTN / 32;
    constexpr int BUF_E  = (BM + BN) * BK;
    constexpr int MAIN_B = 2 * BUF_E * 2;
    constexpr int STG_B  = F32S ? (4 * 16 * RPF * 4) : (4 * 16 * RPH * 2);
    constexpr int SMEM_B = (MAIN_B > STG_B) ? MAIN_B : STG_B;

    __shared__ __align__(16) char smem[SMEM_B];

    const int tid = threadIdx.x;

    // ---- XCD-aware bijective block swizzle ----
    const int gx = gridDim.x, gy = gridDim.y;
    const int nwg = gx * gy * gridDim.z;
    int lin = (blockIdx.z * gy + blockIdx.y) * gx + blockIdx.x;
    int swz = (lin & 7) * (nwg >> 3) + (lin >> 3);
    const int bxi = swz % gx;
    const int tmp = swz / gx;
    const int byi = tmp % gy;
    const int bzi = tmp / gy;

    const int brz = BR2 ? bzi : 0;
    const u16* Ag = brz ? A1 : A0;
    const u16* Bg = brz ? B1 : B0;
    float* Cf     = brz ? C1f : C0f;
    u16*   Ch     = brz ? C1h : C0h;
    const float* bias = brz ? bias1 : bias0;

    const int bm = byi * BM;
    const int bn = bxi * BN;

    const int l   = tid & 63;
    const int wid = tid >> 6;
    const int wm  = wid / WGN;
    const int wn  = wid % WGN;
    const int lr  = l & 15;
    const int lk  = l >> 4;

    size_t aoff[IA]; int albase[IA];
    #pragma unroll
    for (int i = 0; i < IA; ++i) {
        const int s   = (i * 4 + wid) * 64 + l;
        const int row = s / SPR;
        const int c   = (s & SMASK) ^ (row & SMASK);
        aoff[i]   = (size_t)(bm + row) * lda + c * 8;
        albase[i] = (i * 4 + wid) * 64 * 8;
    }
    size_t boff[IB]; int blbase[IB];
    #pragma unroll
    for (int i = 0; i < IB; ++i) {
        const int s   = (i * 4 + wid) * 64 + l;
        const int row = s / SPR;
        const int c   = (s & SMASK) ^ (row & SMASK);
        boff[i]   = (size_t)(bn + row) * ldb + c * 8;
        blbase[i] = (i * 4 + wid) * 64 * 8 + BM * BK;
    }

    f32x4 acc[FM][FN] = {};

    for (int s = 0; s < (DUAL ? 2 : 1); ++s) {
        const u16* As = DUAL ? (s ? A1 : A0) : Ag;
        const u16* Bs = DUAL ? (s ? B1 : B0) : Bg;

        int cur = 0;
        {
            u16* buf = (u16*)smem;
            #pragma unroll
            for (int i = 0; i < IA; ++i) gload_lds16(As + aoff[i], &buf[albase[i]]);
            #pragma unroll
            for (int i = 0; i < IB; ++i) gload_lds16(Bs + boff[i], &buf[blbase[i]]);
        }
        asm volatile("s_waitcnt vmcnt(0)" ::: "memory");
        __syncthreads();

        for (int k0 = 0; k0 < K; k0 += BK) {
            if (k0 + BK < K) {
                u16* nbuf = (u16*)smem + (cur ^ 1) * BUF_E;
                #pragma unroll
                for (int i = 0; i < IA; ++i)
                    gload_lds16(As + aoff[i] + k0 + BK, &nbuf[albase[i]]);
                #pragma unroll
                for (int i = 0; i < IB; ++i)
                    gload_lds16(Bs + boff[i] + k0 + BK, &nbuf[blbase[i]]);
            }
            const u16* Alds = (const u16*)smem + cur * BUF_E;
            const u16* Blds = Alds + BM * BK;

            #pragma unroll
            for (int kh = 0; kh < KH; ++kh) {
                bf16x8 af[FM], bfr[FN];
                #pragma unroll
                for (int m = 0; m < FM; ++m) {
                    int row = wm * WTM + m * 16 + lr;
                    int c   = kh * 4 + lk;
                    af[m] = *(const bf16x8*)(&Alds[(row * SPR + (c ^ (row & SMASK))) * 8]);
                }
                #pragma unroll
                for (int n = 0; n < FN; ++n) {
                    int row = wn * WTN + n * 16 + lr;
                    int c   = kh * 4 + lk;
                    bfr[n] = *(const bf16x8*)(&Blds[(row * SPR + (c ^ (row & SMASK))) * 8]);
                }
                #pragma unroll
                for (int m = 0; m < FM; ++m)
                    #pragma unroll
                    for (int n = 0; n < FN; ++n)
                        acc[m][n] = __builtin_amdgcn_mfma_f32_16x16x32_bf16(
                            af[m], bfr[n], acc[m][n], 0, 0, 0);
            }
            asm volatile("s_waitcnt vmcnt(0)" ::: "memory");
            __syncthreads();
            cur ^= 1;
        }
    }

    // ---- coalesced epilogue: per-wave 16 x WTN slice via LDS ----
    __syncthreads();
    const int rrow = l >> 2;
    const int rc   = (l & 3) * (WTN / 4);

    if (F32S) {
        float* stg = (float*)smem + wid * (16 * RPF);
        #pragma unroll
        for (int m = 0; m < FM; ++m) {
            #pragma unroll
            for (int n = 0; n < FN; ++n)
                #pragma unroll
                for (int j = 0; j < 4; ++j)
                    stg[(lk * 4 + j) * RPF + n * 16 + lr] = acc[m][n][j];
            __syncthreads();
            const int grow = bm + wm * WTM + m * 16 + rrow;
            const int gcol = bn + wn * WTN + rc;
            float4 v[NCF];
            #pragma unroll
            for (int q = 0; q < NCF; ++q)
                v[q] = *(float4*)&stg[rrow * RPF + rc + q * 4];
            if (EPI == 3) {
                #pragma unroll
                for (int q = 0; q < NCF; ++q) {
                    float4 bb = *(const float4*)(bias + gcol + q * 4);
                    float4 rr = *(const float4*)(resid + (size_t)grow * ldc + gcol + q * 4);
                    v[q].x += bb.x + rr.x;  v[q].y += bb.y + rr.y;
                    v[q].z += bb.z + rr.z;  v[q].w += bb.w + rr.w;
                }
            }
            #pragma unroll
            for (int q = 0; q < NCF; ++q)
                *(float4*)(Cf + (size_t)grow * ldc + gcol + q * 4) = v[q];
            if (EPI == 1) {
                #pragma unroll
                for (int q = 0; q < NCH; ++q) {
                    float* vf = (float*)&v[q * 2];
                    uint u0 = (uint)f2bf(vf[0]) | ((uint)f2bf(vf[1]) << 16);
                    uint u1 = (uint)f2bf(vf[2]) | ((uint)f2bf(vf[3]) << 16);
                    uint u2 = (uint)f2bf(vf[4]) | ((uint)f2bf(vf[5]) << 16);
                    uint u3 = (uint)f2bf(vf[6]) | ((uint)f2bf(vf[7]) << 16);
                    *(uint4*)(Ch + (size_t)grow * ldc + gcol + q * 8) =
                        make_uint4(u0, u1, u2, u3);
                }
            }
            __syncthreads();
        }
    } else {
        u16* stg = (u16*)smem + wid * (16 * RPH);
        #pragma unroll
        for (int m = 0; m < FM; ++m) {
            #pragma unroll
            for (int n = 0; n < FN; ++n) {
                float bv = 0.0f;
                if (EPI == 2) bv = bias[bn + wn * WTN + n * 16 + lr];
                #pragma unroll
                for (int j = 0; j < 4; ++j) {
                    float vj = acc[m][n][j];
                    if (EPI == 2) vj = softplus_fast(vj + bv);
                    stg[(lk * 4 + j) * RPH + n * 16 + lr] = f2bf(vj);
                }
            }
            __syncthreads();
            const int grow = bm + wm * WTM + m * 16 + rrow;
            const int gcol = bn + wn * WTN + rc;
            #pragma unroll
            for (int q = 0; q < NCH; ++q) {
                uint4 p = *(uint4*)&stg[rrow * RPH + rc + q * 8];
                *(uint4*)(Ch + (size_t)grow * ldc + gcol + q * 8) = p;
            }
            __syncthreads();
        }
    }
}

// ---------------------------------------------------------------------------
// Depthwise conv k=4 (causal fwd / anticausal bwd) + bias + SiLU -> bf16
// Vectorized: 8 contiguous d-channels per thread (uint4 loads/stores).
// ---------------------------------------------------------------------------
__global__ __launch_bounds__(256) void conv_silu_k(
    const u16* __restrict__ xz0, const u16* __restrict__ xz1,
    const float* __restrict__ w0,  const float* __restrict__ w1,
    const float* __restrict__ cb0, const float* __restrict__ cb1,
    u16* __restrict__ xo0,         u16* __restrict__ xo1)
{
    const int idx = blockIdx.x * 256 + threadIdx.x;   // over 2 * NTOK * 128
    const int br  = idx >> 19;
    const int g   = idx & ((1 << 19) - 1);
    const u16* xin = br ? xz1 : xz0;
    const float* w   = br ? w1  : w0;
    const float* cb  = br ? cb1 : cb0;
    u16* xo          = br ? xo1 : xo0;

    const int d0 = (g & 127) << 3;
    const int t  = g >> 7;
    const int l  = t & (L_SEQ - 1);
    const int base = t - l;

    float acc[8];
    {
        float4 c0 = *(const float4*)(cb + d0);
        float4 c1 = *(const float4*)(cb + d0 + 4);
        acc[0]=c0.x; acc[1]=c0.y; acc[2]=c0.z; acc[3]=c0.w;
        acc[4]=c1.x; acc[5]=c1.y; acc[6]=c1.z; acc[7]=c1.w;
    }
    float wv[8][4];
    #pragma unroll
    for (int i = 0; i < 8; ++i) {
        float4 wf = *(const float4*)(w + (d0 + i) * 4);
        wv[i][0]=wf.x; wv[i][1]=wf.y; wv[i][2]=wf.z; wv[i][3]=wf.w;
    }
    #pragma unroll
    for (int k = 0; k < 4; ++k) {
        // fwd: tap k hits row l-3+k ; bwd: tap k hits row l+3-k
        const int row = br ? (l + 3 - k) : (l - 3 + k);
        if (row >= 0 && row < L_SEQ) {
            uint4 pk = *(const uint4*)(xin + (size_t)(base + row) * 2048 + d0);
            const u16* pv = (const u16*)&pk;
            #pragma unroll
            for (int i = 0; i < 8; ++i)
                acc[i] = fmaf(wv[i][k], bf2f(pv[i]), acc[i]);
        }
    }
    uint4 out;
    uint* op = (uint*)&out;
    #pragma unroll
    for (int q = 0; q < 4; ++q) {
        float a0 = acc[2*q]   * sigmoidf_(acc[2*q]);
        float a1 = acc[2*q+1] * sigmoidf_(acc[2*q+1]);
        op[q] = (uint)f2bf(a0) | ((uint)f2bf(a1) << 16);
    }
    *(uint4*)(xo + (size_t)t * DINNER + d0) = out;
}

// ---------------------------------------------------------------------------
// Chunk-parallel scan (NCHUNK=64, CHUNK=32). Thread owns d; h[16] in regs.
// bid = (((br*2+b)*64 + cc)*4 + dq) ; 1024 blocks -> 4 blocks/CU.
// ---------------------------------------------------------------------------
__global__ __launch_bounds__(256) void scan1_k(
    const u16* __restrict__ dt0, const u16* __restrict__ dt1,
    const u16* __restrict__ xi0, const u16* __restrict__ xi1,
    const float* __restrict__ xd0, const float* __restrict__ xd1,
    const float* __restrict__ Al0, const float* __restrict__ Al1,
    float* __restrict__ hbuf, float* __restrict__ sdtbuf)
{
    const int bid = blockIdx.x;
    const int dq  = bid & 3;
    const int cc  = (bid >> 2) & 63;
    const int b   = (bid >> 8) & 1;
    const int br  = bid >> 9;
    const int rev = br;
    const int p   = rev ? (NCHUNK - 1 - cc) : cc;
    const int tid = threadIdx.x;
    const int d   = dq * 256 + tid;

    const u16* dt = br ? dt1 : dt0;
    const u16* xi = br ? xi1 : xi0;
    const float* xd = br ? xd1 : xd0;
    const float* Al = br ? Al1 : Al0;

    float A2[16];
    #pragma unroll
    for (int i = 0; i < 4; ++i) {
        float4 a = *(const float4*)(Al + (size_t)d * 16 + i * 4);
        A2[i*4+0] = -__expf(a.x) * 1.44269504f;
        A2[i*4+1] = -__expf(a.y) * 1.44269504f;
        A2[i*4+2] = -__expf(a.z) * 1.44269504f;
        A2[i*4+3] = -__expf(a.w) * 1.44269504f;
    }

    __shared__ float s_b[CHUNK][16];
    const int rtB = b * L_SEQ + cc * CHUNK;
    if (tid < 128) {
        int row = tid >> 2, q = (tid & 3) * 4;
        *(float4*)&s_b[row][q] = *(const float4*)(xd + (size_t)(rtB + row) * 64 + 32 + q);
    }
    __syncthreads();

    float h[16] = {};
    float sdt = 0.0f;
    int rr = rev ? (CHUNK - 1) : 0;
    float dtc = bf2f(dt[(size_t)(rtB + rr) * DINNER + d]);
    float xic = bf2f(xi[(size_t)(rtB + rr) * DINNER + d]);

    for (int r = 0; r < CHUNK; ++r) {
        float dtn = 0.0f, xin_ = 0.0f;
        if (r < CHUNK - 1) {
            const int rrn = rev ? (CHUNK - 2 - r) : (r + 1);
            dtn  = bf2f(dt[(size_t)(rtB + rrn) * DINNER + d]);
            xin_ = bf2f(xi[(size_t)(rtB + rrn) * DINNER + d]);
        }
        float bv[16];
        *(float4*)&bv[0]  = *(const float4*)&s_b[rr][0];
        *(float4*)&bv[4]  = *(const float4*)&s_b[rr][4];
        *(float4*)&bv[8]  = *(const float4*)&s_b[rr][8];
        *(float4*)&bv[12] = *(const float4*)&s_b[rr][12];
        const float common = dtc * xic;
        #pragma unroll
        for (int n = 0; n < 16; ++n)
            h[n] = fmaf(exp2f(dtc * A2[n]), h[n], common * bv[n]);
        sdt += dtc;
        dtc = dtn; xic = xin_;
        rr = rev ? (CHUNK - 2 - r) : (r + 1);
    }

    float4* hp = (float4*)(hbuf + ((size_t)((br * 2 + b) * NCHUNK + p) * DINNER + d) * 16);
    hp[0] = make_float4(h[0],  h[1],  h[2],  h[3]);
    hp[1] = make_float4(h[4],  h[5],  h[6],  h[7]);
    hp[2] = make_float4(h[8],  h[9],  h[10], h[11]);
    hp[3] = make_float4(h[12], h[13], h[14], h[15]);
    sdtbuf[(size_t)((br * 2 + b) * NCHUNK + p) * DINNER + d] = sdt;
}

__global__ __launch_bounds__(256) void scan2_k(
    float* __restrict__ hbuf, const float* __restrict__ sdtbuf,
    const float* __restrict__ Al0, const float* __restrict__ Al1)
{
    const int gid = blockIdx.x * 256 + threadIdx.x;
    const int br  = gid >> 15;
    const int b   = (gid >> 14) & 1;
    const int cid = gid & 16383;
    const int d   = cid >> 4;
    const float* Al = br ? Al1 : Al0;
    const float A2 = -__expf(Al[cid]) * 1.44269504f;
    const int bb = (br * 2 + b) * NCHUNK;

    float hi = 0.0f;
    for (int pp = 0; pp < NCHUNK; ++pp) {
        const size_t off = (size_t)(bb + pp) * 16384 + cid;
        const float he = hbuf[off];
        const float ap = exp2f(A2 * sdtbuf[(size_t)(bb + pp) * DINNER + d]);
        hbuf[off] = hi;
        hi = fmaf(ap, hi, he);
    }
}

__global__ __launch_bounds__(256) void scan3_k(
    const u16* __restrict__ dt0, const u16* __restrict__ dt1,
    const u16* __restrict__ xi0, const u16* __restrict__ xi1,
    const u16* __restrict__ xz0, const u16* __restrict__ xz1,
    const float* __restrict__ xd0, const float* __restrict__ xd1,
    u16* __restrict__ y0,          u16* __restrict__ y1,
    const float* __restrict__ Al0, const float* __restrict__ Al1,
    const float* __restrict__ D0,  const float* __restrict__ D1,
    const float* __restrict__ hbuf)
{
    const int bid = blockIdx.x;
    const int dq  = bid & 3;
    const int cc  = (bid >> 2) & 63;
    const int b   = (bid >> 8) & 1;
    const int br  = bid >> 9;
    const int rev = br;
    const int p   = rev ? (NCHUNK - 1 - cc) : cc;
    const int tid = threadIdx.x;
    const int d   = dq * 256 + tid;

    const u16* dt = br ? dt1 : dt0;
    const u16* xi = br ? xi1 : xi0;
    const u16* zz = (br ? xz1 : xz0) + DINNER;
    const float* xd = br ? xd1 : xd0;
    u16* y          = br ? y1  : y0;
    const float* Al = br ? Al1 : Al0;
    const float Dd  = (br ? D1 : D0)[d];

    float A2[16];
    #pragma unroll
    for (int i = 0; i < 4; ++i) {
        float4 a = *(const float4*)(Al + (size_t)d * 16 + i * 4);
        A2[i*4+0] = -__expf(a.x) * 1.44269504f;
        A2[i*4+1] = -__expf(a.y) * 1.44269504f;
        A2[i*4+2] = -__expf(a.z) * 1.44269504f;
        A2[i*4+3] = -__expf(a.w) * 1.44269504f;
    }

    __shared__ float s_bc[CHUNK][32];
    const int rtB = b * L_SEQ + cc * CHUNK;
    {
        int row = tid >> 3, q = (tid & 7) * 4;
        *(float4*)&s_bc[row][q] = *(const float4*)(xd + (size_t)(rtB + row) * 64 + 32 + q);
    }

    float h[16];
    {
        const float4* hp = (const float4*)(hbuf + ((size_t)((br * 2 + b) * NCHUNK + p) * DINNER + d) * 16);
        float4 h0 = hp[0], h1 = hp[1], h2 = hp[2], h3 = hp[3];
        h[0]=h0.x; h[1]=h0.y; h[2]=h0.z; h[3]=h0.w;
        h[4]=h1.x; h[5]=h1.y; h[6]=h1.z; h[7]=h1.w;
        h[8]=h2.x; h[9]=h2.y; h[10]=h2.z; h[11]=h2.w;
        h[12]=h3.x; h[13]=h3.y; h[14]=h3.z; h[15]=h3.w;
    }
    __syncthreads();

    int rr = rev ? (CHUNK - 1) : 0;
    float dtc = bf2f(dt[(size_t)(rtB + rr) * DINNER + d]);
    float xic = bf2f(xi[(size_t)(rtB + rr) * DINNER + d]);
    float zc  = bf2f(zz[(size_t)(rtB + rr) * 2048 + d]);

    for (int r = 0; r < CHUNK; ++r) {
        float dtn = 0.0f, xin_ = 0.0f, zn = 0.0f;
        if (r < CHUNK - 1) {
            const int rrn = rev ? (CHUNK - 2 - r) : (r + 1);
            dtn  = bf2f(dt[(size_t)(rtB + rrn) * DINNER + d]);
            xin_ = bf2f(xi[(size_t)(rtB + rrn) * DINNER + d]);
            zn   = bf2f(zz[(size_t)(rtB + rrn) * 2048 + d]);
        }
        float bv[16], cv[16];
        *(float4*)&bv[0]  = *(const float4*)&s_bc[rr][0];
        *(float4*)&bv[4]  = *(const float4*)&s_bc[rr][4];
        *(float4*)&bv[8]  = *(const float4*)&s_bc[rr][8];
        *(float4*)&bv[12] = *(const float4*)&s_bc[rr][12];
        *(float4*)&cv[0]  = *(const float4*)&s_bc[rr][16];
        *(float4*)&cv[4]  = *(const float4*)&s_bc[rr][20];
        *(float4*)&cv[8]  = *(const float4*)&s_bc[rr][24];
        *(float4*)&cv[12] = *(const float4*)&s_bc[rr][28];
        const float common = dtc * xic;
        float acc = 0.0f;
        #pragma unroll
        for (int n = 0; n < 16; ++n) {
            h[n] = fmaf(exp2f(dtc * A2[n]), h[n], common * bv[n]);
            acc  = fmaf(h[n], cv[n], acc);
        }
        const float yv = (acc + xic * Dd) * (zc * sigmoidf_(zc));
        y[(size_t)(rtB + rr) * DINNER + d] = f2bf(yv);
        dtc = dtn; xic = xin_; zc = zn;
        rr = rev ? (CHUNK - 2 - r) : (r + 1);
    }
}

// ---------------------------------------------------------------------------
extern "C" void kernel_launch(void* const* d_in, const int* in_sizes, int n_in,
                              void* d_out, int out_size, void* d_ws, size_t ws_size,
                              hipStream_t stream)
{
    const float* x      = (const float*)d_in[0];
    const float* ln_g   = (const float*)d_in[1];
    const float* ln_b   = (const float*)d_in[2];
    const float* proj_w = (const float*)d_in[3];
    const float* proj_b = (const float*)d_in[4];
    const float* p_in_w[2]   = {(const float*)d_in[5],  (const float*)d_in[14]};
    const float* p_conv_w[2] = {(const float*)d_in[6],  (const float*)d_in[15]};
    const float* p_conv_b[2] = {(const float*)d_in[7],  (const float*)d_in[16]};
    const float* p_xproj[2]  = {(const float*)d_in[8],  (const float*)d_in[17]};
    const float* p_dt_w[2]   = {(const float*)d_in[9],  (const float*)d_in[18]};
    const float* p_dt_b[2]   = {(const float*)d_in[10], (const float*)d_in[19]};
    const float* p_Alog[2]   = {(const float*)d_in[11], (const float*)d_in[20]};
    const float* p_D[2]      = {(const float*)d_in[12], (const float*)d_in[21]};
    const float* p_out_w[2]  = {(const float*)d_in[13], (const float*)d_in[22]};

    char* w = (char*)d_ws;
    auto alloc = [&](size_t bytes) -> void* {
        void* p = (void*)w;
        w += (bytes + 255) & ~(size_t)255;
        return p;
    };

    u16* xn_bf = (u16*)alloc((size_t)NTOK * DMODEL * 2);
    u16 *in_wT[2], *xprojT[2], *dt_wT[2], *out_w_bf[2], *WcT[2];
    for (int br = 0; br < 2; ++br) {
        in_wT[br]    = (u16*)alloc((size_t)2048 * 512 * 2);
        xprojT[br]   = (u16*)alloc((size_t)64 * 1024 * 2);
        dt_wT[br]    = (u16*)alloc((size_t)1024 * 32 * 2);
        out_w_bf[br] = (u16*)alloc((size_t)1024 * 512 * 2);
        WcT[br]      = (u16*)alloc((size_t)512 * 1024 * 2);
    }
    u16* proj_wT = (u16*)alloc((size_t)512 * 512 * 2);
    float *xdb[2];
    u16 *xz[2], *xi_bf[2], *xdb_bf[2], *dtb[2], *y_bf[2];
    for (int br = 0; br < 2; ++br) {
        xz[br]     = (u16*)alloc((size_t)NTOK * 2048 * 2);
        xi_bf[br]  = (u16*)alloc((size_t)NTOK * DINNER * 2);
        xdb[br]    = (float*)alloc((size_t)NTOK * 64 * 4);
        xdb_bf[br] = (u16*)alloc((size_t)NTOK * 64 * 2);
        dtb[br]    = (u16*)alloc((size_t)NTOK * DINNER * 2);
        y_bf[br]   = (u16*)alloc((size_t)NTOK * DINNER * 2);
    }
    float* hbuf = (float*)alloc((size_t)4 * NCHUNK * 16384 * 4);
    float* sdtb = (float*)alloc((size_t)4 * NCHUNK * DINNER * 4);

    const dim3 blk(256);

    // ---- weight prep ----
    for (int br = 0; br < 2; ++br) {
        tcast_k<<<dim3(2048/32, 512/32), blk, 0, stream>>>(p_in_w[br], in_wT[br], 512, 2048);
        tcast_k<<<dim3(64/32, 1024/32),  blk, 0, stream>>>(p_xproj[br], xprojT[br], 1024, 64);
        tcast_k<<<dim3(1024/32, 32/32),  blk, 0, stream>>>(p_dt_w[br], dt_wT[br], 32, 1024);
        castbf_k<<<(1024*512/8)/256, blk, 0, stream>>>(p_out_w[br], out_w_bf[br]);
    }
    tcast_k<<<dim3(512/32, 512/32), blk, 0, stream>>>(proj_w, proj_wT, 512, 512);

    // ---- WcT[br] = (out_w[br] @ proj_w)^T in bf16 ----
    gemm_bf16_k<64,64,64, 2,2, 4, true,false>
        <<<dim3(1024/64, 512/64, 2), blk, 0, stream>>>(
        proj_wT, proj_wT, 512, out_w_bf[0], out_w_bf[1], 512,
        nullptr, nullptr, WcT[0], WcT[1], 1024, 512, nullptr, nullptr, nullptr);

    // ---- LayerNorm -> bf16 ----
    ln_k<<<NTOK / 4, blk, 0, stream>>>(x, ln_g, ln_b, xn_bf);

    // ---- in-proj (fused xi|z, N=2048) -> bf16, both branches via grid.z ----
    gemm_bf16_k<128,128,64, 2,2, 4, true,false>
        <<<dim3(2048/128, NTOK/128, 2), blk, 0, stream>>>(
        xn_bf, xn_bf, DMODEL, in_wT[0], in_wT[1], DMODEL,
        nullptr, nullptr, xz[0], xz[1], 2048, DMODEL, nullptr, nullptr, nullptr);

    // ---- conv + SiLU -> bf16 (both branches, 8 d/thread) ----
    conv_silu_k<<<2 * NTOK * (DINNER / 8) / 256, blk, 0, stream>>>(
        xz[0], xz[1], p_conv_w[0], p_conv_w[1], p_conv_b[0], p_conv_b[1],
        xi_bf[0], xi_bf[1]);

    // ---- x-proj (N=64) -> fp32 (scan B/C) + bf16 (dt GEMM A), BK=128 ----
    gemm_bf16_k<32,64,128, 2,2, 1, true,false>
        <<<dim3(1, NTOK/32, 2), blk, 0, stream>>>(
        xi_bf[0], xi_bf[1], DINNER, xprojT[0], xprojT[1], DINNER,
        xdb[0], xdb[1], xdb_bf[0], xdb_bf[1], 64, DINNER, nullptr, nullptr, nullptr);

    // ---- dt-proj (K=32) + fast softplus + bias -> bf16 ----
    gemm_bf16_k<128,128,32, 2,2, 2, true,false>
        <<<dim3(DINNER/128, NTOK/128, 2), blk, 0, stream>>>(
        xdb_bf[0], xdb_bf[1], 64, dt_wT[0], dt_wT[1], 32,
        nullptr, nullptr, dtb[0], dtb[1], DINNER, 32, p_dt_b[0], p_dt_b[1], nullptr);

    // ---- chunk-parallel bidirectional scan (1024 blocks per pass) ----
    scan1_k<<<1024, blk, 0, stream>>>(dtb[0], dtb[1], xi_bf[0], xi_bf[1],
                                      xdb[0], xdb[1], p_Alog[0], p_Alog[1],
                                      hbuf, sdtb);
    scan2_k<<<65536 / 256, blk, 0, stream>>>(hbuf, sdtb, p_Alog[0], p_Alog[1]);
    scan3_k<<<1024, blk, 0, stream>>>(dtb[0], dtb[1], xi_bf[0], xi_bf[1],
                                      xz[0], xz[1], xdb[0], xdb[1],
                                      y_bf[0], y_bf[1], p_Alog[0], p_Alog[1],
                                      p_D[0], p_D[1], hbuf);

    // ---- fused out-proj+final: out = y0@Wc0 + y1@Wc1 + proj_b + x, BK=128 ----
    gemm_bf16_k<64,64,128, 2,2, 3, false,true>
        <<<dim3(DMODEL/64, NTOK/64, 1), blk, 0, stream>>>(
        y_bf[0], y_bf[1], DINNER, WcT[0], WcT[1], DINNER,
        (float*)d_out, nullptr, nullptr, nullptr, DMODEL, DINNER,
        proj_b, nullptr, x);
}

// Round 12
// 296.849 us; speedup vs baseline: 1.1574x; 1.1574x over previous
//
#include <hip/hip_runtime.h>
#include <hip/hip_bf16.h>
#include <math.h>

#define L_SEQ  2048
#define NTOK   4096
#define DMODEL 512
#define DINNER 1024
#define DSTATE 16
#define NCHUNK 128
#define CHUNK  16

typedef unsigned short u16;
typedef float f32x4 __attribute__((ext_vector_type(4)));
typedef __bf16 bf16x8 __attribute__((ext_vector_type(8)));

__device__ __forceinline__ float sigmoidf_(float x) {
    return 1.0f / (1.0f + __expf(-x));
}
__device__ __forceinline__ u16 f2bf(float f) {
    __hip_bfloat16 h = __float2bfloat16(f);
    return __builtin_bit_cast(u16, h);
}
__device__ __forceinline__ float bf2f(u16 u) {
    return __bfloat162float(__builtin_bit_cast(__hip_bfloat16, u));
}
__device__ __forceinline__ float softplus_fast(float t) {
    return fmaxf(t, 0.0f) + __logf(1.0f + __expf(-fabsf(t)));
}
__device__ __forceinline__ void gload_lds16(const u16* g, u16* l) {
    __builtin_amdgcn_global_load_lds(
        (const __attribute__((address_space(1))) void*)g,
        (__attribute__((address_space(3))) void*)l, 16, 0, 0);
}

// ---------------------------------------------------------------------------
// Transpose + cast fp32 [R][C] -> bf16 [C][R]
// ---------------------------------------------------------------------------
__global__ __launch_bounds__(256) void tcast_k(const float* __restrict__ in,
                                               u16* __restrict__ out,
                                               int R, int C)
{
    __shared__ u16 t[32][33];
    const int cl = threadIdx.x & 31;
    const int rl = threadIdx.x >> 5;
    const int bc = blockIdx.x << 5;
    const int br = blockIdx.y << 5;
    #pragma unroll
    for (int i = 0; i < 4; ++i) {
        int r = rl + i * 8;
        t[r][cl] = f2bf(in[(size_t)(br + r) * C + bc + cl]);
    }
    __syncthreads();
    #pragma unroll
    for (int i = 0; i < 4; ++i) {
        int r = rl + i * 8;
        out[(size_t)(bc + r) * R + br + cl] = t[cl][r];
    }
}

// ---------------------------------------------------------------------------
// Plain cast fp32 -> bf16 (8 elems/thread)
// ---------------------------------------------------------------------------
__global__ __launch_bounds__(256) void castbf_k(const float* __restrict__ in,
                                                u16* __restrict__ out)
{
    const int i = blockIdx.x * 256 + threadIdx.x;
    float4 a = *(const float4*)(in + (size_t)i * 8);
    float4 b = *(const float4*)(in + (size_t)i * 8 + 4);
    uint p0 = (uint)f2bf(a.x) | ((uint)f2bf(a.y) << 16);
    uint p1 = (uint)f2bf(a.z) | ((uint)f2bf(a.w) << 16);
    uint p2 = (uint)f2bf(b.x) | ((uint)f2bf(b.y) << 16);
    uint p3 = (uint)f2bf(b.z) | ((uint)f2bf(b.w) << 16);
    *(uint4*)(out + (size_t)i * 8) = make_uint4(p0, p1, p2, p3);
}

// ---------------------------------------------------------------------------
// LayerNorm -> bf16 output
// ---------------------------------------------------------------------------
__global__ __launch_bounds__(256) void ln_k(const float* __restrict__ x,
                                            const float* __restrict__ g,
                                            const float* __restrict__ b,
                                            u16* __restrict__ xn)
{
    const int w    = threadIdx.x >> 6;
    const int lane = threadIdx.x & 63;
    const int row  = (blockIdx.x << 2) + w;
    const float* xr = x + (size_t)row * DMODEL;

    float4 v0 = *(const float4*)(xr + lane * 8);
    float4 v1 = *(const float4*)(xr + lane * 8 + 4);

    float s = v0.x + v0.y + v0.z + v0.w + v1.x + v1.y + v1.z + v1.w;
    #pragma unroll
    for (int o = 1; o < 64; o <<= 1) s += __shfl_xor(s, o, 64);
    const float mu = s * (1.0f / DMODEL);

    float d0 = v0.x - mu, d1 = v0.y - mu, d2 = v0.z - mu, d3 = v0.w - mu;
    float d4 = v1.x - mu, d5 = v1.y - mu, d6 = v1.z - mu, d7 = v1.w - mu;
    float ss = d0*d0 + d1*d1 + d2*d2 + d3*d3 + d4*d4 + d5*d5 + d6*d6 + d7*d7;
    #pragma unroll
    for (int o = 1; o < 64; o <<= 1) ss += __shfl_xor(ss, o, 64);
    const float rs = rsqrtf(ss * (1.0f / DMODEL) + 1e-5f);

    float4 g0 = *(const float4*)(g + lane * 8);
    float4 g1 = *(const float4*)(g + lane * 8 + 4);
    float4 b0 = *(const float4*)(b + lane * 8);
    float4 b1 = *(const float4*)(b + lane * 8 + 4);

    u16 o8[8];
    o8[0] = f2bf(d0 * rs * g0.x + b0.x);
    o8[1] = f2bf(d1 * rs * g0.y + b0.y);
    o8[2] = f2bf(d2 * rs * g0.z + b0.z);
    o8[3] = f2bf(d3 * rs * g0.w + b0.w);
    o8[4] = f2bf(d4 * rs * g1.x + b1.x);
    o8[5] = f2bf(d5 * rs * g1.y + b1.y);
    o8[6] = f2bf(d6 * rs * g1.z + b1.z);
    o8[7] = f2bf(d7 * rs * g1.w + b1.w);
    uint pk0 = (uint)o8[0] | ((uint)o8[1] << 16);
    uint pk1 = (uint)o8[2] | ((uint)o8[3] << 16);
    uint pk2 = (uint)o8[4] | ((uint)o8[5] << 16);
    uint pk3 = (uint)o8[6] | ((uint)o8[7] << 16);
    uint4 pk = make_uint4(pk0, pk1, pk2, pk3);
    *(uint4*)(xn + (size_t)row * DMODEL + lane * 8) = pk;
}

// ---------------------------------------------------------------------------
// bf16 MFMA GEMM: C[M,N] = A[M,K] (bf16 rm) x B^T[N,K] (bf16 rm)
// 2-phase double-buffered global_load_lds pipeline; XOR-swizzle on global
// source slot (m173); XCD-aware bijective block swizzle; coalesced epilogue.
// EPI: 1 = fp32 + bf16 dual store, 2 = softplus(acc+bias)->bf16,
//      3 = acc+bias+resid->fp32, 4 = bf16 store
// ---------------------------------------------------------------------------
template<int BM, int BN, int BK, int WGM, int WGN, int EPI, bool BR2, bool DUAL>
__global__ __launch_bounds__(256) void gemm_bf16_k(
    const u16* __restrict__ A0, const u16* __restrict__ A1, int lda,
    const u16* __restrict__ B0, const u16* __restrict__ B1, int ldb,
    float* __restrict__ C0f, float* __restrict__ C1f,
    u16* __restrict__ C0h, u16* __restrict__ C1h, int ldc,
    int K,
    const float* __restrict__ bias0, const float* __restrict__ bias1,
    const float* __restrict__ resid)
{
    constexpr int SPR   = BK / 8;
    constexpr int SMASK = SPR - 1;
    constexpr int IA    = BM * SPR / 256;
    constexpr int IB    = BN * SPR / 256;
    constexpr int WTM   = BM / WGM;
    constexpr int WTN   = BN / WGN;
    constexpr int FM    = WTM / 16;
    constexpr int FN    = WTN / 16;
    constexpr int KH    = BK / 32;
    constexpr bool F32S = (EPI == 1 || EPI == 3);
    constexpr int RPF   = WTN + 4;
    constexpr int RPH   = WTN + 8;
    constexpr int NCF   = WTN / 16;
    constexpr int NCH   = WTN / 32;
    constexpr int BUF_E  = (BM + BN) * BK;
    constexpr int MAIN_B = 2 * BUF_E * 2;
    constexpr int STG_B  = F32S ? (4 * 16 * RPF * 4) : (4 * 16 * RPH * 2);
    constexpr int SMEM_B = (MAIN_B > STG_B) ? MAIN_B : STG_B;

    __shared__ __align__(16) char smem[SMEM_B];

    const int tid = threadIdx.x;

    // ---- XCD-aware bijective block swizzle ----
    const int gx = gridDim.x, gy = gridDim.y;
    const int nwg = gx * gy * gridDim.z;
    int lin = (blockIdx.z * gy + blockIdx.y) * gx + blockIdx.x;
    int swz = (lin & 7) * (nwg >> 3) + (lin >> 3);
    const int bxi = swz % gx;
    const int tmp = swz / gx;
    const int byi = tmp % gy;
    const int bzi = tmp / gy;

    const int brz = BR2 ? bzi : 0;
    const u16* Ag = brz ? A1 : A0;
    const u16* Bg = brz ? B1 : B0;
    float* Cf     = brz ? C1f : C0f;
    u16*   Ch     = brz ? C1h : C0h;
    const float* bias = brz ? bias1 : bias0;

    const int bm = byi * BM;
    const int bn = bxi * BN;

    const int l   = tid & 63;
    const int wid = tid >> 6;
    const int wm  = wid / WGN;
    const int wn  = wid % WGN;
    const int lr  = l & 15;
    const int lk  = l >> 4;

    size_t aoff[IA]; int albase[IA];
    #pragma unroll
    for (int i = 0; i < IA; ++i) {
        const int s   = (i * 4 + wid) * 64 + l;
        const int row = s / SPR;
        const int c   = (s & SMASK) ^ (row & SMASK);
        aoff[i]   = (size_t)(bm + row) * lda + c * 8;
        albase[i] = (i * 4 + wid) * 64 * 8;
    }
    size_t boff[IB]; int blbase[IB];
    #pragma unroll
    for (int i = 0; i < IB; ++i) {
        const int s   = (i * 4 + wid) * 64 + l;
        const int row = s / SPR;
        const int c   = (s & SMASK) ^ (row & SMASK);
        boff[i]   = (size_t)(bn + row) * ldb + c * 8;
        blbase[i] = (i * 4 + wid) * 64 * 8 + BM * BK;
    }

    f32x4 acc[FM][FN] = {};

    for (int s = 0; s < (DUAL ? 2 : 1); ++s) {
        const u16* As = DUAL ? (s ? A1 : A0) : Ag;
        const u16* Bs = DUAL ? (s ? B1 : B0) : Bg;

        int cur = 0;
        {
            u16* buf = (u16*)smem;
            #pragma unroll
            for (int i = 0; i < IA; ++i) gload_lds16(As + aoff[i], &buf[albase[i]]);
            #pragma unroll
            for (int i = 0; i < IB; ++i) gload_lds16(Bs + boff[i], &buf[blbase[i]]);
        }
        asm volatile("s_waitcnt vmcnt(0)" ::: "memory");
        __syncthreads();

        for (int k0 = 0; k0 < K; k0 += BK) {
            if (k0 + BK < K) {
                u16* nbuf = (u16*)smem + (cur ^ 1) * BUF_E;
                #pragma unroll
                for (int i = 0; i < IA; ++i)
                    gload_lds16(As + aoff[i] + k0 + BK, &nbuf[albase[i]]);
                #pragma unroll
                for (int i = 0; i < IB; ++i)
                    gload_lds16(Bs + boff[i] + k0 + BK, &nbuf[blbase[i]]);
            }
            const u16* Alds = (const u16*)smem + cur * BUF_E;
            const u16* Blds = Alds + BM * BK;

            #pragma unroll
            for (int kh = 0; kh < KH; ++kh) {
                bf16x8 af[FM], bfr[FN];
                #pragma unroll
                for (int m = 0; m < FM; ++m) {
                    int row = wm * WTM + m * 16 + lr;
                    int c   = kh * 4 + lk;
                    af[m] = *(const bf16x8*)(&Alds[(row * SPR + (c ^ (row & SMASK))) * 8]);
                }
                #pragma unroll
                for (int n = 0; n < FN; ++n) {
                    int row = wn * WTN + n * 16 + lr;
                    int c   = kh * 4 + lk;
                    bfr[n] = *(const bf16x8*)(&Blds[(row * SPR + (c ^ (row & SMASK))) * 8]);
                }
                #pragma unroll
                for (int m = 0; m < FM; ++m)
                    #pragma unroll
                    for (int n = 0; n < FN; ++n)
                        acc[m][n] = __builtin_amdgcn_mfma_f32_16x16x32_bf16(
                            af[m], bfr[n], acc[m][n], 0, 0, 0);
            }
            asm volatile("s_waitcnt vmcnt(0)" ::: "memory");
            __syncthreads();
            cur ^= 1;
        }
    }

    // ---- coalesced epilogue: per-wave 16 x WTN slice via LDS ----
    __syncthreads();
    const int rrow = l >> 2;
    const int rc   = (l & 3) * (WTN / 4);

    if (F32S) {
        float* stg = (float*)smem + wid * (16 * RPF);
        #pragma unroll
        for (int m = 0; m < FM; ++m) {
            #pragma unroll
            for (int n = 0; n < FN; ++n)
                #pragma unroll
                for (int j = 0; j < 4; ++j)
                    stg[(lk * 4 + j) * RPF + n * 16 + lr] = acc[m][n][j];
            __syncthreads();
            const int grow = bm + wm * WTM + m * 16 + rrow;
            const int gcol = bn + wn * WTN + rc;
            float4 v[NCF];
            #pragma unroll
            for (int q = 0; q < NCF; ++q)
                v[q] = *(float4*)&stg[rrow * RPF + rc + q * 4];
            if (EPI == 3) {
                #pragma unroll
                for (int q = 0; q < NCF; ++q) {
                    float4 bb = *(const float4*)(bias + gcol + q * 4);
                    float4 rr = *(const float4*)(resid + (size_t)grow * ldc + gcol + q * 4);
                    v[q].x += bb.x + rr.x;  v[q].y += bb.y + rr.y;
                    v[q].z += bb.z + rr.z;  v[q].w += bb.w + rr.w;
                }
            }
            #pragma unroll
            for (int q = 0; q < NCF; ++q)
                *(float4*)(Cf + (size_t)grow * ldc + gcol + q * 4) = v[q];
            if (EPI == 1) {
                #pragma unroll
                for (int q = 0; q < NCH; ++q) {
                    float* vf = (float*)&v[q * 2];
                    uint u0 = (uint)f2bf(vf[0]) | ((uint)f2bf(vf[1]) << 16);
                    uint u1 = (uint)f2bf(vf[2]) | ((uint)f2bf(vf[3]) << 16);
                    uint u2 = (uint)f2bf(vf[4]) | ((uint)f2bf(vf[5]) << 16);
                    uint u3 = (uint)f2bf(vf[6]) | ((uint)f2bf(vf[7]) << 16);
                    *(uint4*)(Ch + (size_t)grow * ldc + gcol + q * 8) =
                        make_uint4(u0, u1, u2, u3);
                }
            }
            __syncthreads();
        }
    } else {
        u16* stg = (u16*)smem + wid * (16 * RPH);
        #pragma unroll
        for (int m = 0; m < FM; ++m) {
            #pragma unroll
            for (int n = 0; n < FN; ++n) {
                float bv = 0.0f;
                if (EPI == 2) bv = bias[bn + wn * WTN + n * 16 + lr];
                #pragma unroll
                for (int j = 0; j < 4; ++j) {
                    float vj = acc[m][n][j];
                    if (EPI == 2) vj = softplus_fast(vj + bv);
                    stg[(lk * 4 + j) * RPH + n * 16 + lr] = f2bf(vj);
                }
            }
            __syncthreads();
            const int grow = bm + wm * WTM + m * 16 + rrow;
            const int gcol = bn + wn * WTN + rc;
            #pragma unroll
            for (int q = 0; q < NCH; ++q) {
                uint4 p = *(uint4*)&stg[rrow * RPH + rc + q * 8];
                *(uint4*)(Ch + (size_t)grow * ldc + gcol + q * 8) = p;
            }
            __syncthreads();
        }
    }
}

// ---------------------------------------------------------------------------
// Depthwise conv k=4 (causal fwd / anticausal bwd) + bias + SiLU -> bf16
// Vectorized: 8 contiguous d-channels per thread (uint4 loads/stores).
// ---------------------------------------------------------------------------
__global__ __launch_bounds__(256) void conv_silu_k(
    const u16* __restrict__ xz0, const u16* __restrict__ xz1,
    const float* __restrict__ w0,  const float* __restrict__ w1,
    const float* __restrict__ cb0, const float* __restrict__ cb1,
    u16* __restrict__ xo0,         u16* __restrict__ xo1)
{
    const int idx = blockIdx.x * 256 + threadIdx.x;   // over 2 * NTOK * 128
    const int br  = idx >> 19;
    const int g   = idx & ((1 << 19) - 1);
    const u16* xin = br ? xz1 : xz0;
    const float* w   = br ? w1  : w0;
    const float* cb  = br ? cb1 : cb0;
    u16* xo          = br ? xo1 : xo0;

    const int d0 = (g & 127) << 3;
    const int t  = g >> 7;
    const int l  = t & (L_SEQ - 1);
    const int base = t - l;

    float acc[8];
    {
        float4 c0 = *(const float4*)(cb + d0);
        float4 c1 = *(const float4*)(cb + d0 + 4);
        acc[0]=c0.x; acc[1]=c0.y; acc[2]=c0.z; acc[3]=c0.w;
        acc[4]=c1.x; acc[5]=c1.y; acc[6]=c1.z; acc[7]=c1.w;
    }
    float wv[8][4];
    #pragma unroll
    for (int i = 0; i < 8; ++i) {
        float4 wf = *(const float4*)(w + (d0 + i) * 4);
        wv[i][0]=wf.x; wv[i][1]=wf.y; wv[i][2]=wf.z; wv[i][3]=wf.w;
    }
    #pragma unroll
    for (int k = 0; k < 4; ++k) {
        const int row = br ? (l + 3 - k) : (l - 3 + k);
        if (row >= 0 && row < L_SEQ) {
            uint4 pk = *(const uint4*)(xin + (size_t)(base + row) * 2048 + d0);
            const u16* pv = (const u16*)&pk;
            #pragma unroll
            for (int i = 0; i < 8; ++i)
                acc[i] = fmaf(wv[i][k], bf2f(pv[i]), acc[i]);
        }
    }
    uint4 out;
    uint* op = (uint*)&out;
    #pragma unroll
    for (int q = 0; q < 4; ++q) {
        float a0 = acc[2*q]   * sigmoidf_(acc[2*q]);
        float a1 = acc[2*q+1] * sigmoidf_(acc[2*q+1]);
        op[q] = (uint)f2bf(a0) | ((uint)f2bf(a1) << 16);
    }
    *(uint4*)(xo + (size_t)t * DINNER + d0) = out;
}

// ---------------------------------------------------------------------------
// Chunk-parallel scan (NCHUNK=128, CHUNK=16). Thread owns d; h[16] in regs.
// bid = (((br*2+b)*128 + cc)*4 + dq) ; 2048 blocks -> 8 blocks/CU.
// dA fast path: if A2[n] == (n+1)*A2[0] (detected per wave), use q-powers:
// one exp2 + 15 muls per step instead of 16 exp2.
// ---------------------------------------------------------------------------
__global__ __launch_bounds__(256) void scan1_k(
    const u16* __restrict__ dt0, const u16* __restrict__ dt1,
    const u16* __restrict__ xi0, const u16* __restrict__ xi1,
    const float* __restrict__ xd0, const float* __restrict__ xd1,
    const float* __restrict__ Al0, const float* __restrict__ Al1,
    float* __restrict__ hbuf, float* __restrict__ sdtbuf)
{
    const int bid = blockIdx.x;
    const int dq  = bid & 3;
    const int cc  = (bid >> 2) & 127;
    const int b   = (bid >> 9) & 1;
    const int br  = bid >> 10;
    const int rev = br;
    const int p   = rev ? (NCHUNK - 1 - cc) : cc;
    const int tid = threadIdx.x;
    const int d   = dq * 256 + tid;

    const u16* dt = br ? dt1 : dt0;
    const u16* xi = br ? xi1 : xi0;
    const float* xd = br ? xd1 : xd0;
    const float* Al = br ? Al1 : Al0;

    float A2[16];
    #pragma unroll
    for (int i = 0; i < 4; ++i) {
        float4 a = *(const float4*)(Al + (size_t)d * 16 + i * 4);
        A2[i*4+0] = -__expf(a.x) * 1.44269504f;
        A2[i*4+1] = -__expf(a.y) * 1.44269504f;
        A2[i*4+2] = -__expf(a.z) * 1.44269504f;
        A2[i*4+3] = -__expf(a.w) * 1.44269504f;
    }
    bool fa = true;
    #pragma unroll
    for (int n = 1; n < 16; ++n)
        fa = fa && (fabsf(A2[n] / A2[0] - (float)(n + 1)) < 1e-3f * (float)(n + 1));
    const bool okA = (bool)__all(fa ? 1 : 0);

    __shared__ float s_b[CHUNK][16];
    const int rtB = b * L_SEQ + cc * CHUNK;
    if (tid < CHUNK * 4) {
        int row = tid >> 2, q = (tid & 3) * 4;
        *(float4*)&s_b[row][q] = *(const float4*)(xd + (size_t)(rtB + row) * 64 + 32 + q);
    }
    __syncthreads();

    float h[16] = {};
    float sdt = 0.0f;
    int rr = rev ? (CHUNK - 1) : 0;
    float dtc = bf2f(dt[(size_t)(rtB + rr) * DINNER + d]);
    float xic = bf2f(xi[(size_t)(rtB + rr) * DINNER + d]);

    if (okA) {
        for (int r = 0; r < CHUNK; ++r) {
            float dtn = 0.0f, xin_ = 0.0f;
            if (r < CHUNK - 1) {
                const int rrn = rev ? (CHUNK - 2 - r) : (r + 1);
                dtn  = bf2f(dt[(size_t)(rtB + rrn) * DINNER + d]);
                xin_ = bf2f(xi[(size_t)(rtB + rrn) * DINNER + d]);
            }
            float bv[16];
            *(float4*)&bv[0]  = *(const float4*)&s_b[rr][0];
            *(float4*)&bv[4]  = *(const float4*)&s_b[rr][4];
            *(float4*)&bv[8]  = *(const float4*)&s_b[rr][8];
            *(float4*)&bv[12] = *(const float4*)&s_b[rr][12];
            const float common = dtc * xic;
            const float q = exp2f(dtc * A2[0]);
            float pw = q;
            #pragma unroll
            for (int n = 0; n < 16; ++n) {
                h[n] = fmaf(pw, h[n], common * bv[n]);
                pw *= q;
            }
            sdt += dtc;
            dtc = dtn; xic = xin_;
            rr = rev ? (CHUNK - 2 - r) : (r + 1);
        }
    } else {
        for (int r = 0; r < CHUNK; ++r) {
            float dtn = 0.0f, xin_ = 0.0f;
            if (r < CHUNK - 1) {
                const int rrn = rev ? (CHUNK - 2 - r) : (r + 1);
                dtn  = bf2f(dt[(size_t)(rtB + rrn) * DINNER + d]);
                xin_ = bf2f(xi[(size_t)(rtB + rrn) * DINNER + d]);
            }
            float bv[16];
            *(float4*)&bv[0]  = *(const float4*)&s_b[rr][0];
            *(float4*)&bv[4]  = *(const float4*)&s_b[rr][4];
            *(float4*)&bv[8]  = *(const float4*)&s_b[rr][8];
            *(float4*)&bv[12] = *(const float4*)&s_b[rr][12];
            const float common = dtc * xic;
            #pragma unroll
            for (int n = 0; n < 16; ++n)
                h[n] = fmaf(exp2f(dtc * A2[n]), h[n], common * bv[n]);
            sdt += dtc;
            dtc = dtn; xic = xin_;
            rr = rev ? (CHUNK - 2 - r) : (r + 1);
        }
    }

    float4* hp = (float4*)(hbuf + ((size_t)((br * 2 + b) * NCHUNK + p) * DINNER + d) * 16);
    hp[0] = make_float4(h[0],  h[1],  h[2],  h[3]);
    hp[1] = make_float4(h[4],  h[5],  h[6],  h[7]);
    hp[2] = make_float4(h[8],  h[9],  h[10], h[11]);
    hp[3] = make_float4(h[12], h[13], h[14], h[15]);
    sdtbuf[(size_t)((br * 2 + b) * NCHUNK + p) * DINNER + d] = sdt;
}

// scan2: sequential chunk-combine with 8-deep load prefetch.
__global__ __launch_bounds__(256) void scan2_k(
    float* __restrict__ hbuf, const float* __restrict__ sdtbuf,
    const float* __restrict__ Al0, const float* __restrict__ Al1)
{
    const int gid = blockIdx.x * 256 + threadIdx.x;
    const int br  = gid >> 15;
    const int b   = (gid >> 14) & 1;
    const int cid = gid & 16383;
    const int d   = cid >> 4;
    const float* Al = br ? Al1 : Al0;
    const float A2 = -__expf(Al[cid]) * 1.44269504f;
    const int bb = (br * 2 + b) * NCHUNK;

    float he[8], sd[8];
    #pragma unroll
    for (int i = 0; i < 8; ++i) {
        he[i] = hbuf[(size_t)(bb + i) * 16384 + cid];
        sd[i] = sdtbuf[(size_t)(bb + i) * DINNER + d];
    }
    float hi = 0.0f;
    for (int pp = 0; pp < NCHUNK; pp += 8) {
        float he2[8], sd2[8];
        if (pp + 8 < NCHUNK) {
            #pragma unroll
            for (int i = 0; i < 8; ++i) {
                he2[i] = hbuf[(size_t)(bb + pp + 8 + i) * 16384 + cid];
                sd2[i] = sdtbuf[(size_t)(bb + pp + 8 + i) * DINNER + d];
            }
        }
        #pragma unroll
        for (int i = 0; i < 8; ++i) {
            const float ap = exp2f(A2 * sd[i]);
            hbuf[(size_t)(bb + pp + i) * 16384 + cid] = hi;
            hi = fmaf(ap, hi, he[i]);
        }
        #pragma unroll
        for (int i = 0; i < 8; ++i) { he[i] = he2[i]; sd[i] = sd2[i]; }
    }
}

__global__ __launch_bounds__(256) void scan3_k(
    const u16* __restrict__ dt0, const u16* __restrict__ dt1,
    const u16* __restrict__ xi0, const u16* __restrict__ xi1,
    const u16* __restrict__ xz0, const u16* __restrict__ xz1,
    const float* __restrict__ xd0, const float* __restrict__ xd1,
    u16* __restrict__ y0,          u16* __restrict__ y1,
    const float* __restrict__ Al0, const float* __restrict__ Al1,
    const float* __restrict__ D0,  const float* __restrict__ D1,
    const float* __restrict__ hbuf)
{
    const int bid = blockIdx.x;
    const int dq  = bid & 3;
    const int cc  = (bid >> 2) & 127;
    const int b   = (bid >> 9) & 1;
    const int br  = bid >> 10;
    const int rev = br;
    const int p   = rev ? (NCHUNK - 1 - cc) : cc;
    const int tid = threadIdx.x;
    const int d   = dq * 256 + tid;

    const u16* dt = br ? dt1 : dt0;
    const u16* xi = br ? xi1 : xi0;
    const u16* zz = (br ? xz1 : xz0) + DINNER;
    const float* xd = br ? xd1 : xd0;
    u16* y          = br ? y1  : y0;
    const float* Al = br ? Al1 : Al0;
    const float Dd  = (br ? D1 : D0)[d];

    float A2[16];
    #pragma unroll
    for (int i = 0; i < 4; ++i) {
        float4 a = *(const float4*)(Al + (size_t)d * 16 + i * 4);
        A2[i*4+0] = -__expf(a.x) * 1.44269504f;
        A2[i*4+1] = -__expf(a.y) * 1.44269504f;
        A2[i*4+2] = -__expf(a.z) * 1.44269504f;
        A2[i*4+3] = -__expf(a.w) * 1.44269504f;
    }
    bool fa = true;
    #pragma unroll
    for (int n = 1; n < 16; ++n)
        fa = fa && (fabsf(A2[n] / A2[0] - (float)(n + 1)) < 1e-3f * (float)(n + 1));
    const bool okA = (bool)__all(fa ? 1 : 0);

    __shared__ float s_bc[CHUNK][32];
    const int rtB = b * L_SEQ + cc * CHUNK;
    if (tid < CHUNK * 8) {
        int row = tid >> 3, q = (tid & 7) * 4;
        *(float4*)&s_bc[row][q] = *(const float4*)(xd + (size_t)(rtB + row) * 64 + 32 + q);
    }

    float h[16];
    {
        const float4* hp = (const float4*)(hbuf + ((size_t)((br * 2 + b) * NCHUNK + p) * DINNER + d) * 16);
        float4 h0 = hp[0], h1 = hp[1], h2 = hp[2], h3 = hp[3];
        h[0]=h0.x; h[1]=h0.y; h[2]=h0.z; h[3]=h0.w;
        h[4]=h1.x; h[5]=h1.y; h[6]=h1.z; h[7]=h1.w;
        h[8]=h2.x; h[9]=h2.y; h[10]=h2.z; h[11]=h2.w;
        h[12]=h3.x; h[13]=h3.y; h[14]=h3.z; h[15]=h3.w;
    }
    __syncthreads();

    int rr = rev ? (CHUNK - 1) : 0;
    float dtc = bf2f(dt[(size_t)(rtB + rr) * DINNER + d]);
    float xic = bf2f(xi[(size_t)(rtB + rr) * DINNER + d]);
    float zc  = bf2f(zz[(size_t)(rtB + rr) * 2048 + d]);

    if (okA) {
        for (int r = 0; r < CHUNK; ++r) {
            float dtn = 0.0f, xin_ = 0.0f, zn = 0.0f;
            if (r < CHUNK - 1) {
                const int rrn = rev ? (CHUNK - 2 - r) : (r + 1);
                dtn  = bf2f(dt[(size_t)(rtB + rrn) * DINNER + d]);
                xin_ = bf2f(xi[(size_t)(rtB + rrn) * DINNER + d]);
                zn   = bf2f(zz[(size_t)(rtB + rrn) * 2048 + d]);
            }
            float bv[16], cv[16];
            *(float4*)&bv[0]  = *(const float4*)&s_bc[rr][0];
            *(float4*)&bv[4]  = *(const float4*)&s_bc[rr][4];
            *(float4*)&bv[8]  = *(const float4*)&s_bc[rr][8];
            *(float4*)&bv[12] = *(const float4*)&s_bc[rr][12];
            *(float4*)&cv[0]  = *(const float4*)&s_bc[rr][16];
            *(float4*)&cv[4]  = *(const float4*)&s_bc[rr][20];
            *(float4*)&cv[8]  = *(const float4*)&s_bc[rr][24];
            *(float4*)&cv[12] = *(const float4*)&s_bc[rr][28];
            const float common = dtc * xic;
            const float q = exp2f(dtc * A2[0]);
            float pw = q;
            float acc = 0.0f;
            #pragma unroll
            for (int n = 0; n < 16; ++n) {
                h[n] = fmaf(pw, h[n], common * bv[n]);
                acc  = fmaf(h[n], cv[n], acc);
                pw *= q;
            }
            const float yv = (acc + xic * Dd) * (zc * sigmoidf_(zc));
            y[(size_t)(rtB + rr) * DINNER + d] = f2bf(yv);
            dtc = dtn; xic = xin_; zc = zn;
            rr = rev ? (CHUNK - 2 - r) : (r + 1);
        }
    } else {
        for (int r = 0; r < CHUNK; ++r) {
            float dtn = 0.0f, xin_ = 0.0f, zn = 0.0f;
            if (r < CHUNK - 1) {
                const int rrn = rev ? (CHUNK - 2 - r) : (r + 1);
                dtn  = bf2f(dt[(size_t)(rtB + rrn) * DINNER + d]);
                xin_ = bf2f(xi[(size_t)(rtB + rrn) * DINNER + d]);
                zn   = bf2f(zz[(size_t)(rtB + rrn) * 2048 + d]);
            }
            float bv[16], cv[16];
            *(float4*)&bv[0]  = *(const float4*)&s_bc[rr][0];
            *(float4*)&bv[4]  = *(const float4*)&s_bc[rr][4];
            *(float4*)&bv[8]  = *(const float4*)&s_bc[rr][8];
            *(float4*)&bv[12] = *(const float4*)&s_bc[rr][12];
            *(float4*)&cv[0]  = *(const float4*)&s_bc[rr][16];
            *(float4*)&cv[4]  = *(const float4*)&s_bc[rr][20];
            *(float4*)&cv[8]  = *(const float4*)&s_bc[rr][24];
            *(float4*)&cv[12] = *(const float4*)&s_bc[rr][28];
            const float common = dtc * xic;
            float acc = 0.0f;
            #pragma unroll
            for (int n = 0; n < 16; ++n) {
                h[n] = fmaf(exp2f(dtc * A2[n]), h[n], common * bv[n]);
                acc  = fmaf(h[n], cv[n], acc);
            }
            const float yv = (acc + xic * Dd) * (zc * sigmoidf_(zc));
            y[(size_t)(rtB + rr) * DINNER + d] = f2bf(yv);
            dtc = dtn; xic = xin_; zc = zn;
            rr = rev ? (CHUNK - 2 - r) : (r + 1);
        }
    }
}

// ---------------------------------------------------------------------------
extern "C" void kernel_launch(void* const* d_in, const int* in_sizes, int n_in,
                              void* d_out, int out_size, void* d_ws, size_t ws_size,
                              hipStream_t stream)
{
    const float* x      = (const float*)d_in[0];
    const float* ln_g   = (const float*)d_in[1];
    const float* ln_b   = (const float*)d_in[2];
    const float* proj_w = (const float*)d_in[3];
    const float* proj_b = (const float*)d_in[4];
    const float* p_in_w[2]   = {(const float*)d_in[5],  (const float*)d_in[14]};
    const float* p_conv_w[2] = {(const float*)d_in[6],  (const float*)d_in[15]};
    const float* p_conv_b[2] = {(const float*)d_in[7],  (const float*)d_in[16]};
    const float* p_xproj[2]  = {(const float*)d_in[8],  (const float*)d_in[17]};
    const float* p_dt_w[2]   = {(const float*)d_in[9],  (const float*)d_in[18]};
    const float* p_dt_b[2]   = {(const float*)d_in[10], (const float*)d_in[19]};
    const float* p_Alog[2]   = {(const float*)d_in[11], (const float*)d_in[20]};
    const float* p_D[2]      = {(const float*)d_in[12], (const float*)d_in[21]};
    const float* p_out_w[2]  = {(const float*)d_in[13], (const float*)d_in[22]};

    char* w = (char*)d_ws;
    auto alloc = [&](size_t bytes) -> void* {
        void* p = (void*)w;
        w += (bytes + 255) & ~(size_t)255;
        return p;
    };

    u16* xn_bf = (u16*)alloc((size_t)NTOK * DMODEL * 2);
    u16 *in_wT[2], *xprojT[2], *dt_wT[2], *out_w_bf[2], *WcT[2];
    for (int br = 0; br < 2; ++br) {
        in_wT[br]    = (u16*)alloc((size_t)2048 * 512 * 2);
        xprojT[br]   = (u16*)alloc((size_t)64 * 1024 * 2);
        dt_wT[br]    = (u16*)alloc((size_t)1024 * 32 * 2);
        out_w_bf[br] = (u16*)alloc((size_t)1024 * 512 * 2);
        WcT[br]      = (u16*)alloc((size_t)512 * 1024 * 2);
    }
    u16* proj_wT = (u16*)alloc((size_t)512 * 512 * 2);
    float *xdb[2];
    u16 *xz[2], *xi_bf[2], *xdb_bf[2], *dtb[2], *y_bf[2];
    for (int br = 0; br < 2; ++br) {
        xz[br]     = (u16*)alloc((size_t)NTOK * 2048 * 2);
        xi_bf[br]  = (u16*)alloc((size_t)NTOK * DINNER * 2);
        xdb[br]    = (float*)alloc((size_t)NTOK * 64 * 4);
        xdb_bf[br] = (u16*)alloc((size_t)NTOK * 64 * 2);
        dtb[br]    = (u16*)alloc((size_t)NTOK * DINNER * 2);
        y_bf[br]   = (u16*)alloc((size_t)NTOK * DINNER * 2);
    }
    float* hbuf = (float*)alloc((size_t)4 * NCHUNK * 16384 * 4);
    float* sdtb = (float*)alloc((size_t)4 * NCHUNK * DINNER * 4);

    const dim3 blk(256);

    // ---- weight prep ----
    for (int br = 0; br < 2; ++br) {
        tcast_k<<<dim3(2048/32, 512/32), blk, 0, stream>>>(p_in_w[br], in_wT[br], 512, 2048);
        tcast_k<<<dim3(64/32, 1024/32),  blk, 0, stream>>>(p_xproj[br], xprojT[br], 1024, 64);
        tcast_k<<<dim3(1024/32, 32/32),  blk, 0, stream>>>(p_dt_w[br], dt_wT[br], 32, 1024);
        castbf_k<<<(1024*512/8)/256, blk, 0, stream>>>(p_out_w[br], out_w_bf[br]);
    }
    tcast_k<<<dim3(512/32, 512/32), blk, 0, stream>>>(proj_w, proj_wT, 512, 512);

    // ---- WcT[br] = (out_w[br] @ proj_w)^T in bf16 ----
    gemm_bf16_k<64,64,64, 2,2, 4, true,false>
        <<<dim3(1024/64, 512/64, 2), blk, 0, stream>>>(
        proj_wT, proj_wT, 512, out_w_bf[0], out_w_bf[1], 512,
        nullptr, nullptr, WcT[0], WcT[1], 1024, 512, nullptr, nullptr, nullptr);

    // ---- LayerNorm -> bf16 ----
    ln_k<<<NTOK / 4, blk, 0, stream>>>(x, ln_g, ln_b, xn_bf);

    // ---- in-proj (fused xi|z, N=2048) -> bf16, both branches via grid.z ----
    gemm_bf16_k<128,128,64, 2,2, 4, true,false>
        <<<dim3(2048/128, NTOK/128, 2), blk, 0, stream>>>(
        xn_bf, xn_bf, DMODEL, in_wT[0], in_wT[1], DMODEL,
        nullptr, nullptr, xz[0], xz[1], 2048, DMODEL, nullptr, nullptr, nullptr);

    // ---- conv + SiLU -> bf16 (both branches, 8 d/thread) ----
    conv_silu_k<<<2 * NTOK * (DINNER / 8) / 256, blk, 0, stream>>>(
        xz[0], xz[1], p_conv_w[0], p_conv_w[1], p_conv_b[0], p_conv_b[1],
        xi_bf[0], xi_bf[1]);

    // ---- x-proj (N=64) -> fp32 (scan B/C) + bf16 (dt GEMM A), BK=128 ----
    gemm_bf16_k<32,64,128, 2,2, 1, true,false>
        <<<dim3(1, NTOK/32, 2), blk, 0, stream>>>(
        xi_bf[0], xi_bf[1], DINNER, xprojT[0], xprojT[1], DINNER,
        xdb[0], xdb[1], xdb_bf[0], xdb_bf[1], 64, DINNER, nullptr, nullptr, nullptr);

    // ---- dt-proj (K=32) + fast softplus + bias -> bf16 ----
    gemm_bf16_k<128,128,32, 2,2, 2, true,false>
        <<<dim3(DINNER/128, NTOK/128, 2), blk, 0, stream>>>(
        xdb_bf[0], xdb_bf[1], 64, dt_wT[0], dt_wT[1], 32,
        nullptr, nullptr, dtb[0], dtb[1], DINNER, 32, p_dt_b[0], p_dt_b[1], nullptr);

    // ---- chunk-parallel bidirectional scan (2048 blocks per pass) ----
    scan1_k<<<2048, blk, 0, stream>>>(dtb[0], dtb[1], xi_bf[0], xi_bf[1],
                                      xdb[0], xdb[1], p_Alog[0], p_Alog[1],
                                      hbuf, sdtb);
    scan2_k<<<65536 / 256, blk, 0, stream>>>(hbuf, sdtb, p_Alog[0], p_Alog[1]);
    scan3_k<<<2048, blk, 0, stream>>>(dtb[0], dtb[1], xi_bf[0], xi_bf[1],
                                      xz[0], xz[1], xdb[0], xdb[1],
                                      y_bf[0], y_bf[1], p_Alog[0], p_Alog[1],
                                      p_D[0], p_D[1], hbuf);

    // ---- fused out-proj+final: out = y0@Wc0 + y1@Wc1 + proj_b + x, BK=128 ----
    gemm_bf16_k<64,64,128, 2,2, 3, false,true>
        <<<dim3(DMODEL/64, NTOK/64, 1), blk, 0, stream>>>(
        y_bf[0], y_bf[1], DINNER, WcT[0], WcT[1], DINNER,
        (float*)d_out, nullptr, nullptr, nullptr, DMODEL, DINNER,
        proj_b, nullptr, x);
}